// Round 1
// baseline (358.785 us; speedup 1.0000x reference)
//
#include <hip/hip_runtime.h>
#include <hip/hip_bf16.h>
#include <math.h>

#define S_LEN 2048
#define FDIM  512
#define NH    8
#define HD    64
#define MH_ELEMS (S_LEN * FDIM)          // 1048576
#define MEAN_ELEMS (S_LEN * S_LEN)       // 4194304

// ---------------- Kernel 1: LayerNorm + positional-encoding row 0 ----------------
// pe[:B] with B==1 broadcasts pe[0,:] = (sin(0), cos(0), ...) = (0,1,0,1,...)
__global__ __launch_bounds__(256) void ln_pe_kernel(const float* __restrict__ x,
                                                    const float* __restrict__ gamma,
                                                    const float* __restrict__ beta,
                                                    float* __restrict__ xo) {
    const int row = blockIdx.x;
    const int tid = threadIdx.x;
    const float2 v = ((const float2*)(x + (size_t)row * FDIM))[tid]; // elems 2*tid, 2*tid+1
    float s = v.x + v.y;
    float q = v.x * v.x + v.y * v.y;
    #pragma unroll
    for (int off = 1; off < 64; off <<= 1) {
        s += __shfl_xor(s, off, 64);
        q += __shfl_xor(q, off, 64);
    }
    __shared__ float red[8];
    const int wave = tid >> 6;
    if ((tid & 63) == 0) { red[wave] = s; red[4 + wave] = q; }
    __syncthreads();
    s = red[0] + red[1] + red[2] + red[3];
    q = red[4] + red[5] + red[6] + red[7];
    const float mu  = s * (1.0f / FDIM);
    const float var = q * (1.0f / FDIM) - mu * mu;
    const float rstd = rsqrtf(var + 1e-5f);
    const int f0 = tid * 2, f1 = tid * 2 + 1;
    float o0 = (v.x - mu) * rstd * gamma[f0] + beta[f0];          // even f: +sin(0)=0
    float o1 = (v.y - mu) * rstd * gamma[f1] + beta[f1] + 1.0f;   // odd  f: +cos(0)=1
    ((float2*)(xo + (size_t)row * FDIM))[tid] = make_float2(o0, o1);
}

// ---------------- Kernel 2: per-head QKV projections (fp32 tiled GEMM) ----------------
// C[h][s][d] = sum_f x[s][f] * W[h][f][d];  grid = (Mtiles=32, heads=8, z=Q/K/V)
__global__ __launch_bounds__(256) void qkv_kernel(const float* __restrict__ xw,
                                                  const float* __restrict__ Wq,
                                                  const float* __restrict__ Wk,
                                                  const float* __restrict__ Wv,
                                                  float* __restrict__ Qo,
                                                  float* __restrict__ Ko,
                                                  float* __restrict__ Vo) {
    const int ms0 = blockIdx.x * 64;
    const int h   = blockIdx.y;
    const int z   = blockIdx.z;
    const float* W  = (z == 0) ? Wq : (z == 1) ? Wk : Wv;
    float*       Co = (z == 0) ? Qo : (z == 1) ? Ko : Vo;
    W  += (size_t)h * FDIM * HD;
    Co += (size_t)h * S_LEN * HD;

    __shared__ float As[32][68];  // A transposed: As[kk][m], padded stride (272B, 16B-aligned)
    __shared__ float Bs[32][68];  // Bs[kk][c]

    const int tid = threadIdx.x;
    const int tx = tid & 15, ty = tid >> 4;
    float acc[4][4] = {};

    for (int k0 = 0; k0 < FDIM; k0 += 32) {
        #pragma unroll
        for (int l = 0; l < 2; ++l) {
            const int qidx = tid + l * 256;      // 0..511
            const int m  = qidx >> 3;            // 0..63
            const int ko = (qidx & 7) * 4;       // 0..28
            const float4 a = *(const float4*)(xw + (size_t)(ms0 + m) * FDIM + k0 + ko);
            As[ko + 0][m] = a.x; As[ko + 1][m] = a.y; As[ko + 2][m] = a.z; As[ko + 3][m] = a.w;
        }
        #pragma unroll
        for (int l = 0; l < 2; ++l) {
            const int qidx = tid + l * 256;
            const int kk = qidx >> 4;            // 0..31
            const int co = (qidx & 15) * 4;      // 0..60
            *(float4*)(&Bs[kk][co]) = *(const float4*)(W + (size_t)(k0 + kk) * HD + co);
        }
        __syncthreads();
        #pragma unroll
        for (int kk = 0; kk < 32; ++kk) {
            const float4 a = *(const float4*)(&As[kk][ty * 4]);
            const float4 b = *(const float4*)(&Bs[kk][tx * 4]);
            const float av[4] = {a.x, a.y, a.z, a.w};
            const float bv[4] = {b.x, b.y, b.z, b.w};
            #pragma unroll
            for (int i = 0; i < 4; ++i)
                #pragma unroll
                for (int j = 0; j < 4; ++j)
                    acc[i][j] += av[i] * bv[j];
        }
        __syncthreads();
    }
    #pragma unroll
    for (int i = 0; i < 4; ++i) {
        *(float4*)(Co + (size_t)(ms0 + ty * 4 + i) * HD + tx * 4) =
            make_float4(acc[i][0], acc[i][1], acc[i][2], acc[i][3]);
    }
}

// ---------------- Kernel 3: attention (scores+bias -> softmax -> P export -> PV) ----------------
// grid = (rowtiles=256, heads=8); block = 256 threads; 8 query rows per block.
// sc[8][2048] fp32 = exactly 64KB LDS.
__global__ __launch_bounds__(256, 2) void attn_kernel(const float* __restrict__ Qw,
                                                      const float* __restrict__ Kw,
                                                      const float* __restrict__ Vw,
                                                      __hip_bfloat16* __restrict__ Pw, // may be null
                                                      float* __restrict__ out) {
    const int s0 = blockIdx.x * 8;
    const int h  = blockIdx.y;
    const float* Qh = Qw + (size_t)h * S_LEN * HD;
    const float* Kh = Kw + (size_t)h * S_LEN * HD;
    const float* Vh = Vw + (size_t)h * S_LEN * HD;

    __shared__ float sc[8][S_LEN];
    const int tid = threadIdx.x;

    // ---- Phase B: scores = QK^T/8 + gaussian bias ----
    {
        float acc[8][8] = {};  // [j(col group)][r(row)]
        for (int kc = 0; kc < 4; ++kc) {
            const int d0 = kc * 16;
            float4 kv[8][4];
            #pragma unroll
            for (int j = 0; j < 8; ++j) {
                const float4* kp = (const float4*)(Kh + (size_t)(j * 256 + tid) * HD + d0);
                kv[j][0] = kp[0]; kv[j][1] = kp[1]; kv[j][2] = kp[2]; kv[j][3] = kp[3];
            }
            #pragma unroll
            for (int r = 0; r < 8; ++r) {
                const float4* qp = (const float4*)(Qh + (size_t)(s0 + r) * HD + d0);
                float4 qv[4];
                qv[0] = qp[0]; qv[1] = qp[1]; qv[2] = qp[2]; qv[3] = qp[3];
                #pragma unroll
                for (int j = 0; j < 8; ++j) {
                    float d = 0.f;
                    #pragma unroll
                    for (int i = 0; i < 4; ++i) {
                        d += qv[i].x * kv[j][i].x + qv[i].y * kv[j][i].y
                           + qv[i].z * kv[j][i].z + qv[i].w * kv[j][i].w;
                    }
                    acc[j][r] += d;
                }
            }
        }
        #pragma unroll
        for (int j = 0; j < 8; ++j) {
            const int c = j * 256 + tid;
            #pragma unroll
            for (int r = 0; r < 8; ++r) {
                const float dd = (float)(s0 + r - c);
                sc[r][c] = acc[j][r] * 0.125f + __expf(-0.5f * dd * dd);
            }
        }
    }
    __syncthreads();

    // ---- Phase C: exact softmax per row (one wave per 2 rows) + export P ----
    {
        const int wave = tid >> 6, lane = tid & 63;
        #pragma unroll
        for (int rr = 0; rr < 2; ++rr) {
            const int r = wave * 2 + rr;
            float v[32];
            float m = -1e30f;
            #pragma unroll
            for (int k = 0; k < 32; ++k) { v[k] = sc[r][k * 64 + lane]; m = fmaxf(m, v[k]); }
            #pragma unroll
            for (int off = 1; off < 64; off <<= 1) m = fmaxf(m, __shfl_xor(m, off, 64));
            float ssum = 0.f;
            #pragma unroll
            for (int k = 0; k < 32; ++k) { v[k] = __expf(v[k] - m); ssum += v[k]; }
            #pragma unroll
            for (int off = 1; off < 64; off <<= 1) ssum += __shfl_xor(ssum, off, 64);
            const float inv = 1.0f / ssum;
            if (Pw) {
                __hip_bfloat16* Pr = Pw + ((size_t)h * S_LEN + (s0 + r)) * S_LEN;
                #pragma unroll
                for (int k = 0; k < 32; ++k) {
                    const float p = v[k] * inv;
                    sc[r][k * 64 + lane] = p;
                    Pr[k * 64 + lane] = __float2bfloat16(p);
                }
            } else {
                float* mean_out = out + MH_ELEMS + (size_t)(s0 + r) * S_LEN;
                #pragma unroll
                for (int k = 0; k < 32; ++k) {
                    const float p = v[k] * inv;
                    sc[r][k * 64 + lane] = p;
                    atomicAdd(mean_out + k * 64 + lane, p * 0.125f);
                }
            }
        }
    }
    __syncthreads();

    // ---- Phase D: O = P @ V  (16 t-stripes x 16 d-groups) ----
    const int dgrp   = tid & 15;   // d = dgrp*4 .. +3
    const int stripe = tid >> 4;   // 0..15
    float accO[8][4] = {};
    for (int k = 0; k < 128; ++k) {
        const int t = k * 16 + stripe;
        const float4 vv = *(const float4*)(Vh + (size_t)t * HD + dgrp * 4);
        #pragma unroll
        for (int r = 0; r < 8; ++r) {
            const float p = sc[r][t];  // broadcast across the 16 dgrp lanes
            accO[r][0] += p * vv.x; accO[r][1] += p * vv.y;
            accO[r][2] += p * vv.z; accO[r][3] += p * vv.w;
        }
    }
    __syncthreads();   // everyone done reading sc
    float* part = &sc[0][0];       // reuse LDS: part[stripe][r][dgrp][4] = 32KB
    #pragma unroll
    for (int r = 0; r < 8; ++r)
        *(float4*)(part + ((size_t)(stripe * 8 + r) * 16 + dgrp) * 4) =
            make_float4(accO[r][0], accO[r][1], accO[r][2], accO[r][3]);
    __syncthreads();
    #pragma unroll
    for (int l = 0; l < 2; ++l) {
        const int idx = tid + l * 256;      // 0..511
        const int r = idx >> 6, d = idx & 63;
        float sum = 0.f;
        #pragma unroll
        for (int sp = 0; sp < 16; ++sp)
            sum += part[((size_t)(sp * 8 + r) * 16 + (d >> 2)) * 4 + (d & 3)];
        out[(size_t)(s0 + r) * FDIM + h * HD + d] = sum;
    }
}

// ---------------- Kernel 4: mean over heads of P (bf16 -> fp32) ----------------
__global__ __launch_bounds__(256) void mean_kernel(const __hip_bfloat16* __restrict__ Pw,
                                                   float* __restrict__ out) {
    const size_t idx = (size_t)blockIdx.x * 256 + threadIdx.x;  // 0..4194303
    float sum = 0.f;
    #pragma unroll
    for (int h = 0; h < NH; ++h)
        sum += __bfloat162float(Pw[(size_t)h * MEAN_ELEMS + idx]);
    out[MH_ELEMS + idx] = sum * 0.125f;
}

extern "C" void kernel_launch(void* const* d_in, const int* in_sizes, int n_in,
                              void* d_out, int out_size, void* d_ws, size_t ws_size,
                              hipStream_t stream) {
    const float* x  = (const float*)d_in[0];
    const float* Wq = (const float*)d_in[1];
    const float* Wk = (const float*)d_in[2];
    const float* Wv = (const float*)d_in[3];
    const float* g  = (const float*)d_in[4];
    const float* b  = (const float*)d_in[5];
    float* out = (float*)d_out;
    char* ws = (char*)d_ws;

    float* xw = (float*)(ws);                       // 4 MB
    float* Qw = (float*)(ws + (4ull << 20));        // 4 MB
    float* Kw = (float*)(ws + (8ull << 20));        // 4 MB
    float* Vw = (float*)(ws + (12ull << 20));       // 4 MB
    __hip_bfloat16* Pw = (__hip_bfloat16*)(ws + (16ull << 20));  // 64 MB
    const bool use_p = ws_size >= (80ull << 20);

    ln_pe_kernel<<<S_LEN, 256, 0, stream>>>(x, g, b, xw);
    qkv_kernel<<<dim3(32, 8, 3), 256, 0, stream>>>(xw, Wq, Wk, Wv, Qw, Kw, Vw);
    if (!use_p) {
        hipMemsetAsync(out + MH_ELEMS, 0, (size_t)MEAN_ELEMS * sizeof(float), stream);
    }
    attn_kernel<<<dim3(256, 8), 256, 0, stream>>>(Qw, Kw, Vw, use_p ? Pw : nullptr, out);
    if (use_p) {
        mean_kernel<<<MEAN_ELEMS / 256, 256, 0, stream>>>(Pw, out);
    }
}

// Round 2
// 191.006 us; speedup vs baseline: 1.8784x; 1.8784x over previous
//
#include <hip/hip_runtime.h>
#include <hip/hip_bf16.h>
#include <math.h>

#define S_LEN 2048
#define FDIM  512
#define NH    8
#define HD    64
#define MH_ELEMS (S_LEN * FDIM)          // 1048576
#define MEAN_ELEMS (S_LEN * S_LEN)       // 4194304

typedef _Float16 half_t;
typedef _Float16 half2v __attribute__((ext_vector_type(2)));
typedef _Float16 half8v __attribute__((ext_vector_type(8)));
typedef float    float4v __attribute__((ext_vector_type(4)));

#define MFMA16(a, b, c) __builtin_amdgcn_mfma_f32_16x16x32_f16((a), (b), (c), 0, 0, 0)

// ---------------- Kernel 1: LayerNorm + PE row 0 -> f16 ----------------
// pe[:1] broadcasts pe[0,:] = (0,1,0,1,...): add 1.0 to odd features.
__global__ __launch_bounds__(256) void ln_pe_kernel(const float* __restrict__ x,
                                                    const float* __restrict__ gamma,
                                                    const float* __restrict__ beta,
                                                    half_t* __restrict__ xo) {
    const int row = blockIdx.x;
    const int tid = threadIdx.x;
    const float2 v = ((const float2*)(x + (size_t)row * FDIM))[tid];
    float s = v.x + v.y;
    float q = v.x * v.x + v.y * v.y;
    #pragma unroll
    for (int off = 1; off < 64; off <<= 1) {
        s += __shfl_xor(s, off, 64);
        q += __shfl_xor(q, off, 64);
    }
    __shared__ float red[8];
    const int wave = tid >> 6;
    if ((tid & 63) == 0) { red[wave] = s; red[4 + wave] = q; }
    __syncthreads();
    s = red[0] + red[1] + red[2] + red[3];
    q = red[4] + red[5] + red[6] + red[7];
    const float mu  = s * (1.0f / FDIM);
    const float var = q * (1.0f / FDIM) - mu * mu;
    const float rstd = rsqrtf(var + 1e-5f);
    const int f0 = tid * 2, f1 = tid * 2 + 1;
    const float o0 = (v.x - mu) * rstd * gamma[f0] + beta[f0];
    const float o1 = (v.y - mu) * rstd * gamma[f1] + beta[f1] + 1.0f;
    half2v o; o.x = (half_t)o0; o.y = (half_t)o1;
    ((half2v*)(xo + (size_t)row * FDIM))[tid] = o;
}

// ---------------- Kernel 2: QKV projections via f16 MFMA ----------------
// C[h][s][d] = sum_f xh[s][f] * W[h][f][d]. grid=(16 row-tiles of 128, 8 heads, 3)
__global__ __launch_bounds__(256) void qkv_kernel(const half_t* __restrict__ xh,
                                                  const float* __restrict__ Wq,
                                                  const float* __restrict__ Wk,
                                                  const float* __restrict__ Wv,
                                                  half_t* __restrict__ Qo,
                                                  half_t* __restrict__ Ko,
                                                  half_t* __restrict__ Vo) {
    const int ms0 = blockIdx.x * 128;
    const int h   = blockIdx.y;
    const int z   = blockIdx.z;
    const float* W = ((z == 0) ? Wq : (z == 1) ? Wk : Wv) + (size_t)h * FDIM * HD;
    half_t* Co = ((z == 0) ? Qo : (z == 1) ? Ko : Vo) + (size_t)h * S_LEN * HD;

    __shared__ half_t Xs[128][40];   // [row][k], pad 32->40 (80B stride, 16B aligned, 2-way banks)
    __shared__ half_t Wt[64][40];    // W transposed: [d][k]

    const int tid  = threadIdx.x;
    const int wv   = tid >> 6, lane = tid & 63;
    const int lo   = lane & 15, qq  = lane >> 4;

    const float4v zero4 = {0.f, 0.f, 0.f, 0.f};
    float4v acc[2][4];
    #pragma unroll
    for (int rg = 0; rg < 2; ++rg)
        #pragma unroll
        for (int cg = 0; cg < 4; ++cg) acc[rg][cg] = zero4;

    for (int k0 = 0; k0 < FDIM; k0 += 32) {
        #pragma unroll
        for (int it = 0; it < 2; ++it) {
            const int idx = tid + it * 256;      // 0..511
            const int r = idx >> 2, ch = idx & 3;
            *(half8v*)&Xs[r][ch * 8] = *(const half8v*)(xh + (size_t)(ms0 + r) * FDIM + k0 + ch * 8);
        }
        #pragma unroll
        for (int it = 0; it < 2; ++it) {
            const int idx = tid + it * 256;
            const int kr = idx >> 4, dc = idx & 15;   // 32 k-rows x 16 chunks of 4 fp32
            const float4 w4 = *(const float4*)(W + (size_t)(k0 + kr) * HD + dc * 4);
            Wt[dc * 4 + 0][kr] = (half_t)w4.x;
            Wt[dc * 4 + 1][kr] = (half_t)w4.y;
            Wt[dc * 4 + 2][kr] = (half_t)w4.z;
            Wt[dc * 4 + 3][kr] = (half_t)w4.w;
        }
        __syncthreads();
        half8v a[2], b[4];
        #pragma unroll
        for (int rg = 0; rg < 2; ++rg) a[rg] = *(const half8v*)&Xs[wv * 32 + rg * 16 + lo][qq * 8];
        #pragma unroll
        for (int cg = 0; cg < 4; ++cg) b[cg] = *(const half8v*)&Wt[cg * 16 + lo][qq * 8];
        #pragma unroll
        for (int rg = 0; rg < 2; ++rg)
            #pragma unroll
            for (int cg = 0; cg < 4; ++cg) acc[rg][cg] = MFMA16(a[rg], b[cg], acc[rg][cg]);
        __syncthreads();
    }
    // epilogue: C layout col=lane&15, row=4*(lane>>4)+reg
    #pragma unroll
    for (int rg = 0; rg < 2; ++rg)
        #pragma unroll
        for (int cg = 0; cg < 4; ++cg)
            #pragma unroll
            for (int r = 0; r < 4; ++r)
                Co[(size_t)(ms0 + wv * 32 + rg * 16 + qq * 4 + r) * HD + cg * 16 + lo] =
                    (half_t)acc[rg][cg][r];
}

// ---------------- Kernel 3: fused attention (two-pass flash, MFMA) ----------------
// grid=(64 q-tiles of 32 rows, 8 heads), block=256 (4 waves: rg=wave&1, ch=wave>>1)
__global__ __launch_bounds__(256) void attn_kernel(const half_t* __restrict__ Qw,
                                                   const half_t* __restrict__ Kw,
                                                   const half_t* __restrict__ Vw,
                                                   half_t* __restrict__ Pg,
                                                   float* __restrict__ out,
                                                   const int use_p) {
    const int s0 = blockIdx.x * 32;
    const int h  = blockIdx.y;
    const half_t* Qh = Qw + (size_t)h * S_LEN * HD;
    const half_t* Kh = Kw + (size_t)h * S_LEN * HD;
    const half_t* Vh = Vw + (size_t)h * S_LEN * HD;

    __shared__ half_t Ks[128][72];    // K tile [t][d], stride 144B (2-way banks)
    __shared__ half_t Vt[64][136];    // V tile transposed [d][t], stride 272B
    __shared__ half_t Ps[32][136];    // P tile [row][t]
    __shared__ float  mred[2][32], lred[2][32];

    const int tid  = threadIdx.x;
    const int wv   = tid >> 6, lane = tid & 63;
    const int rg   = wv & 1,  ch    = wv >> 1;
    const int lo   = lane & 15, qq  = lane >> 4;

    // Q fragments (A-operand), direct from global: row=lane&15, k contiguous
    half8v aq[2];
    #pragma unroll
    for (int kk = 0; kk < 2; ++kk)
        aq[kk] = *(const half8v*)(Qh + (size_t)(s0 + rg * 16 + lo) * HD + kk * 32 + qq * 8);

    float mrun[4], lrun[4];
    #pragma unroll
    for (int r = 0; r < 4; ++r) { mrun[r] = -1e30f; lrun[r] = 0.f; }

    // ---- pass 1: online max/sum over all column tiles ----
    for (int nt = 0; nt < 16; ++nt) {
        const int t0 = nt * 128;
        #pragma unroll
        for (int it = 0; it < 4; ++it) {
            const int idx = tid + it * 256;             // 0..1023
            const int r = idx >> 3, c = idx & 7;
            *(half8v*)&Ks[r][c * 8] = *(const half8v*)(Kh + (size_t)(t0 + r) * HD + c * 8);
        }
        __syncthreads();
        float sv[4][4];
        #pragma unroll
        for (int ct = 0; ct < 4; ++ct) {
            const half8v b0 = *(const half8v*)&Ks[ch * 64 + ct * 16 + lo][qq * 8];
            const half8v b1 = *(const half8v*)&Ks[ch * 64 + ct * 16 + lo][32 + qq * 8];
            float4v c4 = {0.f, 0.f, 0.f, 0.f};
            c4 = MFMA16(aq[0], b0, c4);
            c4 = MFMA16(aq[1], b1, c4);
            const int colg = t0 + ch * 64 + ct * 16 + lo;
            #pragma unroll
            for (int r = 0; r < 4; ++r) {
                const float dd = (float)(s0 + rg * 16 + qq * 4 + r - colg);
                sv[ct][r] = c4[r] * 0.125f + __expf(-0.5f * dd * dd);
            }
        }
        #pragma unroll
        for (int r = 0; r < 4; ++r) {
            float tm = fmaxf(fmaxf(sv[0][r], sv[1][r]), fmaxf(sv[2][r], sv[3][r]));
            #pragma unroll
            for (int mk = 1; mk < 16; mk <<= 1) tm = fmaxf(tm, __shfl_xor(tm, mk, 64));
            const float mn  = fmaxf(mrun[r], tm);
            const float scl = __expf(mrun[r] - mn);
            float rs = 0.f;
            #pragma unroll
            for (int ct = 0; ct < 4; ++ct) rs += __expf(sv[ct][r] - mn);
            #pragma unroll
            for (int mk = 1; mk < 16; mk <<= 1) rs += __shfl_xor(rs, mk, 64);
            lrun[r] = lrun[r] * scl + rs;
            mrun[r] = mn;
        }
        __syncthreads();
    }

    // ---- merge the two column halves ----
    if (lo == 0) {
        #pragma unroll
        for (int r = 0; r < 4; ++r) {
            mred[ch][rg * 16 + qq * 4 + r] = mrun[r];
            lred[ch][rg * 16 + qq * 4 + r] = lrun[r];
        }
    }
    __syncthreads();
    float mfin[4], minv[4];
    #pragma unroll
    for (int r = 0; r < 4; ++r) {
        const int row = rg * 16 + qq * 4 + r;
        const float m0 = mred[0][row], m1 = mred[1][row];
        const float mm = fmaxf(m0, m1);
        const float ll = lred[0][row] * __expf(m0 - mm) + lred[1][row] * __expf(m1 - mm);
        mfin[r] = mm; minv[r] = 1.f / ll;
    }
    __syncthreads();

    const float4v zero4 = {0.f, 0.f, 0.f, 0.f};
    float4v accO[2]; accO[0] = zero4; accO[1] = zero4;

    // ---- pass 2: recompute scores -> P -> export + PV ----
    for (int nt = 0; nt < 16; ++nt) {
        const int t0 = nt * 128;
        #pragma unroll
        for (int it = 0; it < 4; ++it) {
            const int idx = tid + it * 256;
            const int r = idx >> 3, c = idx & 7;
            *(half8v*)&Ks[r][c * 8] = *(const half8v*)(Kh + (size_t)(t0 + r) * HD + c * 8);
        }
        #pragma unroll
        for (int it = 0; it < 4; ++it) {
            const int idx = tid + it * 256;
            const int t = idx >> 3, dc = idx & 7;
            const half8v v8 = *(const half8v*)(Vh + (size_t)(t0 + t) * HD + dc * 8);
            #pragma unroll
            for (int j = 0; j < 8; ++j) Vt[dc * 8 + j][t] = v8[j];
        }
        __syncthreads();
        #pragma unroll
        for (int ct = 0; ct < 4; ++ct) {
            const half8v b0 = *(const half8v*)&Ks[ch * 64 + ct * 16 + lo][qq * 8];
            const half8v b1 = *(const half8v*)&Ks[ch * 64 + ct * 16 + lo][32 + qq * 8];
            float4v c4 = {0.f, 0.f, 0.f, 0.f};
            c4 = MFMA16(aq[0], b0, c4);
            c4 = MFMA16(aq[1], b1, c4);
            const int colg = t0 + ch * 64 + ct * 16 + lo;
            #pragma unroll
            for (int r = 0; r < 4; ++r) {
                const float dd = (float)(s0 + rg * 16 + qq * 4 + r - colg);
                const float s = c4[r] * 0.125f + __expf(-0.5f * dd * dd);
                const float p = __expf(s - mfin[r]) * minv[r];
                Ps[rg * 16 + qq * 4 + r][ch * 64 + ct * 16 + lo] = (half_t)p;
            }
        }
        __syncthreads();
        // export P tile (coalesced from LDS)
        {
            const int row = tid >> 3, cc = (tid & 7) * 16;
            const half8v p0 = *(const half8v*)&Ps[row][cc];
            const half8v p1 = *(const half8v*)&Ps[row][cc + 8];
            if (use_p) {
                half_t* dst = Pg + (size_t)h * MEAN_ELEMS + (size_t)(s0 + row) * S_LEN + t0 + cc;
                *(half8v*)dst = p0;
                *(half8v*)(dst + 8) = p1;
            } else {
                float* mo = out + MH_ELEMS + (size_t)(s0 + row) * S_LEN + t0 + cc;
                #pragma unroll
                for (int j = 0; j < 8; ++j) {
                    atomicAdd(mo + j,     (float)p0[j] * 0.125f);
                    atomicAdd(mo + 8 + j, (float)p1[j] * 0.125f);
                }
            }
        }
        // PV: O[32][64], A=Ps rows, B=Vt (d in lane&15, t contiguous)
        #pragma unroll
        for (int ks = 0; ks < 4; ++ks) {
            const half8v ap = *(const half8v*)&Ps[rg * 16 + lo][ks * 32 + qq * 8];
            #pragma unroll
            for (int dgi = 0; dgi < 2; ++dgi) {
                const half8v bv = *(const half8v*)&Vt[(ch * 2 + dgi) * 16 + lo][ks * 32 + qq * 8];
                accO[dgi] = MFMA16(ap, bv, accO[dgi]);
            }
        }
        __syncthreads();
    }

    #pragma unroll
    for (int dgi = 0; dgi < 2; ++dgi)
        #pragma unroll
        for (int r = 0; r < 4; ++r)
            out[(size_t)(s0 + rg * 16 + qq * 4 + r) * FDIM + h * HD + (ch * 2 + dgi) * 16 + lo] =
                accO[dgi][r];
}

// ---------------- Kernel 4: mean over heads of P ----------------
__global__ __launch_bounds__(256) void mean_kernel(const half_t* __restrict__ Pg,
                                                   float* __restrict__ out) {
    const size_t idx = ((size_t)blockIdx.x * 256 + threadIdx.x) * 8;  // 4M elems / 8
    float acc[8] = {0.f, 0.f, 0.f, 0.f, 0.f, 0.f, 0.f, 0.f};
    #pragma unroll
    for (int hh = 0; hh < NH; ++hh) {
        const half8v p = *(const half8v*)(Pg + (size_t)hh * MEAN_ELEMS + idx);
        #pragma unroll
        for (int j = 0; j < 8; ++j) acc[j] += (float)p[j];
    }
    float* o = out + MH_ELEMS + idx;
    *(float4*)o       = make_float4(acc[0] * 0.125f, acc[1] * 0.125f, acc[2] * 0.125f, acc[3] * 0.125f);
    *(float4*)(o + 4) = make_float4(acc[4] * 0.125f, acc[5] * 0.125f, acc[6] * 0.125f, acc[7] * 0.125f);
}

extern "C" void kernel_launch(void* const* d_in, const int* in_sizes, int n_in,
                              void* d_out, int out_size, void* d_ws, size_t ws_size,
                              hipStream_t stream) {
    const float* x  = (const float*)d_in[0];
    const float* Wq = (const float*)d_in[1];
    const float* Wk = (const float*)d_in[2];
    const float* Wv = (const float*)d_in[3];
    const float* g  = (const float*)d_in[4];
    const float* b  = (const float*)d_in[5];
    float* out = (float*)d_out;
    char*  ws  = (char*)d_ws;

    half_t* xh = (half_t*)(ws);                  // 2 MB
    half_t* Qh = (half_t*)(ws + (2ull << 20));   // 2 MB
    half_t* Kh = (half_t*)(ws + (4ull << 20));   // 2 MB
    half_t* Vh = (half_t*)(ws + (6ull << 20));   // 2 MB
    half_t* Pg = (half_t*)(ws + (8ull << 20));   // 64 MB
    const bool use_p = ws_size >= (72ull << 20);

    ln_pe_kernel<<<S_LEN, 256, 0, stream>>>(x, g, b, xh);
    qkv_kernel<<<dim3(16, 8, 3), 256, 0, stream>>>(xh, Wq, Wk, Wv, Qh, Kh, Vh);
    if (!use_p) {
        hipMemsetAsync(out + MH_ELEMS, 0, (size_t)MEAN_ELEMS * sizeof(float), stream);
    }
    attn_kernel<<<dim3(64, 8), 256, 0, stream>>>(Qh, Kh, Vh, Pg, out, use_p ? 1 : 0);
    if (use_p) {
        mean_kernel<<<MEAN_ELEMS / 8 / 256, 256, 0, stream>>>(Pg, out);
    }
}

// Round 3
// 190.472 us; speedup vs baseline: 1.8837x; 1.0028x over previous
//
#include <hip/hip_runtime.h>
#include <hip/hip_bf16.h>
#include <math.h>

#define S_LEN 2048
#define FDIM  512
#define NH    8
#define HD    64
#define MH_ELEMS (S_LEN * FDIM)          // 1048576
#define MEAN_ELEMS (S_LEN * S_LEN)       // 4194304

typedef _Float16 half_t;
typedef _Float16 half2v __attribute__((ext_vector_type(2)));
typedef _Float16 half4v __attribute__((ext_vector_type(4)));
typedef _Float16 half8v __attribute__((ext_vector_type(8)));
typedef float    float4v __attribute__((ext_vector_type(4)));

#define MFMA16(a, b, c) __builtin_amdgcn_mfma_f32_16x16x32_f16((a), (b), (c), 0, 0, 0)

#define VT_STRIDE 260   // halves; 520B rows: b64-aligned, conflict-free writes & b64 reads
#define PS_STRIDE 264   // halves; 528B rows: b128-aligned, free b128 reads, 4-way tiny writes

// ---------------- Kernel 1: LayerNorm + PE row 0 -> f16 ----------------
// pe[:1] broadcasts pe[0,:] = (0,1,0,1,...): add 1.0 to odd features.
__global__ __launch_bounds__(256) void ln_pe_kernel(const float* __restrict__ x,
                                                    const float* __restrict__ gamma,
                                                    const float* __restrict__ beta,
                                                    half_t* __restrict__ xo) {
    const int row = blockIdx.x;
    const int tid = threadIdx.x;
    const float2 v = ((const float2*)(x + (size_t)row * FDIM))[tid];
    float s = v.x + v.y;
    float q = v.x * v.x + v.y * v.y;
    #pragma unroll
    for (int off = 1; off < 64; off <<= 1) {
        s += __shfl_xor(s, off, 64);
        q += __shfl_xor(q, off, 64);
    }
    __shared__ float red[8];
    const int wave = tid >> 6;
    if ((tid & 63) == 0) { red[wave] = s; red[4 + wave] = q; }
    __syncthreads();
    s = red[0] + red[1] + red[2] + red[3];
    q = red[4] + red[5] + red[6] + red[7];
    const float mu  = s * (1.0f / FDIM);
    const float var = q * (1.0f / FDIM) - mu * mu;
    const float rstd = rsqrtf(var + 1e-5f);
    const int f0 = tid * 2, f1 = tid * 2 + 1;
    const float o0 = (v.x - mu) * rstd * gamma[f0] + beta[f0];
    const float o1 = (v.y - mu) * rstd * gamma[f1] + beta[f1] + 1.0f;
    half2v o; o.x = (half_t)o0; o.y = (half_t)o1;
    ((half2v*)(xo + (size_t)row * FDIM))[tid] = o;
}

// ---------------- Kernel 2: QKV projections, LDS-free MFMA ----------------
// A-frag (x rows) and B-frag (W cols, fp32->f16 in regs) loaded直接 from global/L2.
__global__ __launch_bounds__(256) void qkv_kernel(const half_t* __restrict__ xh,
                                                  const float* __restrict__ Wq,
                                                  const float* __restrict__ Wk,
                                                  const float* __restrict__ Wv,
                                                  half_t* __restrict__ Qo,
                                                  half_t* __restrict__ Ko,
                                                  half_t* __restrict__ Vo) {
    const int ms0 = blockIdx.x * 128;
    const int h   = blockIdx.y;
    const int z   = blockIdx.z;
    const float* W = ((z == 0) ? Wq : (z == 1) ? Wk : Wv) + (size_t)h * FDIM * HD;
    half_t* Co = ((z == 0) ? Qo : (z == 1) ? Ko : Vo) + (size_t)h * S_LEN * HD;

    const int tid = threadIdx.x;
    const int wv = tid >> 6, lane = tid & 63;
    const int lo = lane & 15, qq = lane >> 4;

    const float4v zero4 = {0.f, 0.f, 0.f, 0.f};
    float4v acc[2][4];
    #pragma unroll
    for (int rg = 0; rg < 2; ++rg)
        #pragma unroll
        for (int cg = 0; cg < 4; ++cg) acc[rg][cg] = zero4;

    for (int k0 = 0; k0 < FDIM; k0 += 32) {
        half8v a[2];
        #pragma unroll
        for (int rg = 0; rg < 2; ++rg)
            a[rg] = *(const half8v*)(xh + (size_t)(ms0 + wv * 32 + rg * 16 + lo) * FDIM + k0 + qq * 8);
        half8v bw[4];
        #pragma unroll
        for (int cg = 0; cg < 4; ++cg)
            #pragma unroll
            for (int j = 0; j < 8; ++j)
                bw[cg][j] = (half_t)W[(size_t)(k0 + qq * 8 + j) * HD + cg * 16 + lo];
        #pragma unroll
        for (int rg = 0; rg < 2; ++rg)
            #pragma unroll
            for (int cg = 0; cg < 4; ++cg) acc[rg][cg] = MFMA16(a[rg], bw[cg], acc[rg][cg]);
    }
    #pragma unroll
    for (int rg = 0; rg < 2; ++rg)
        #pragma unroll
        for (int cg = 0; cg < 4; ++cg)
            #pragma unroll
            for (int r = 0; r < 4; ++r)
                Co[(size_t)(ms0 + wv * 32 + rg * 16 + qq * 4 + r) * HD + cg * 16 + lo] =
                    (half_t)acc[rg][cg][r];
}

// ---------------- Kernel 3: row sums of exp(scores) -> 1/l ----------------
// No-max softmax denominators. grid=(128 q-tiles of 16, 8 heads). LDS-free K-frags.
__global__ __launch_bounds__(256) void lsum_kernel(const half_t* __restrict__ Qw,
                                                   const half_t* __restrict__ Kw,
                                                   float* __restrict__ linv) {
    const int s0 = blockIdx.x * 16;
    const int h  = blockIdx.y;
    const half_t* Qh = Qw + (size_t)h * S_LEN * HD;
    const half_t* Kh = Kw + (size_t)h * S_LEN * HD;

    const int tid = threadIdx.x;
    const int wv = tid >> 6, lane = tid & 63;
    const int lo = lane & 15, qq = lane >> 4;

    const half8v aq0 = *(const half8v*)(Qh + (size_t)(s0 + lo) * HD + qq * 8);
    const half8v aq1 = *(const half8v*)(Qh + (size_t)(s0 + lo) * HD + 32 + qq * 8);

    float esum[4] = {0.f, 0.f, 0.f, 0.f};
    for (int j = 0; j < 32; ++j) {
        const int cbase = (wv + 4 * j) * 16;
        const half8v b0 = *(const half8v*)(Kh + (size_t)(cbase + lo) * HD + qq * 8);
        const half8v b1 = *(const half8v*)(Kh + (size_t)(cbase + lo) * HD + 32 + qq * 8);
        float4v c4 = {0.f, 0.f, 0.f, 0.f};
        c4 = MFMA16(aq0, b0, c4);
        c4 = MFMA16(aq1, b1, c4);
        const int dd0 = cbase - s0;
        const bool near = (dd0 > -24) && (dd0 < 24);
        #pragma unroll
        for (int r = 0; r < 4; ++r) {
            float s = c4[r] * 0.125f;
            if (near) {
                const float d = (float)(s0 + qq * 4 + r - cbase - lo);
                s += __expf(-0.5f * d * d);
            }
            s = fminf(s, 60.f);
            esum[r] += __expf(s);
        }
    }
    // reduce over the 16 lo-lanes (bits 0..3 of lane id)
    #pragma unroll
    for (int r = 0; r < 4; ++r) {
        #pragma unroll
        for (int mk = 1; mk < 16; mk <<= 1) esum[r] += __shfl_xor(esum[r], mk, 64);
    }
    __shared__ float red[4][16];
    if (lo == 0) {
        #pragma unroll
        for (int r = 0; r < 4; ++r) red[wv][qq * 4 + r] = esum[r];
    }
    __syncthreads();
    if (tid < 16) {
        const float l = red[0][tid] + red[1][tid] + red[2][tid] + red[3][tid];
        linv[(size_t)h * S_LEN + s0 + tid] = 1.0f / l;
    }
}

// ---------------- Kernel 4: attention, heads-in-block, direct mean ----------------
// grid = (64 q-tiles of 32 rows, 8 kv-chunks of 256 cols). 4 waves: rg=wv&1, chw=wv>>1.
__global__ __launch_bounds__(256, 3) void attn_kernel(const half_t* __restrict__ Qw,
                                                      const half_t* __restrict__ Kw,
                                                      const half_t* __restrict__ Vw,
                                                      const float* __restrict__ linv,
                                                      float* __restrict__ partial,
                                                      float* __restrict__ out) {
    const int s0 = blockIdx.x * 32;
    const int c0 = blockIdx.y * 256;

    __shared__ half_t Vt[64 * VT_STRIDE];     // V^T: [d][t], 33.3 KB
    __shared__ half_t Ps[32 * PS_STRIDE];     // P tile [row][t], 16.9 KB

    const int tid = threadIdx.x;
    const int wv = tid >> 6, lane = tid & 63;
    const int rg = wv & 1, chw = wv >> 1;
    const int lo = lane & 15, qq = lane >> 4;
    const int rbase = s0 + rg * 16;
    const int tlow = tid & 31, dcs = tid >> 5;   // V-staging coords (t spread across wave)

    float msum[8][4];
    #pragma unroll
    for (int ct = 0; ct < 8; ++ct)
        #pragma unroll
        for (int r = 0; r < 4; ++r) msum[ct][r] = 0.f;

    float* po = partial + (size_t)blockIdx.y * (size_t)MH_ELEMS;

    for (int h = 0; h < NH; ++h) {
        const half_t* Qh = Qw + (size_t)h * S_LEN * HD;
        const half_t* Kh = Kw + (size_t)h * S_LEN * HD;
        const half_t* Vh = Vw + (size_t)h * S_LEN * HD;
        __syncthreads();   // prev iteration's PV readers done before Vt/Ps overwrite
        // ---- stage V^T (writes hit 32 distinct banks, 2-way => free) ----
        #pragma unroll
        for (int it = 0; it < 8; ++it) {
            const int t = tlow + 32 * it;
            const half8v v8 = *(const half8v*)(Vh + (size_t)(c0 + t) * HD + dcs * 8);
            #pragma unroll
            for (int j = 0; j < 8; ++j) Vt[(size_t)(dcs * 8 + j) * VT_STRIDE + t] = v8[j];
        }
        // ---- QK (global-direct fragments; overlaps V staging latency) ----
        const half8v aq0 = *(const half8v*)(Qh + (size_t)(rbase + lo) * HD + qq * 8);
        const half8v aq1 = *(const half8v*)(Qh + (size_t)(rbase + lo) * HD + 32 + qq * 8);
        float li[4];
        #pragma unroll
        for (int r = 0; r < 4; ++r) li[r] = linv[(size_t)h * S_LEN + rbase + qq * 4 + r];
        #pragma unroll
        for (int ct = 0; ct < 8; ++ct) {
            const int cbase = c0 + chw * 128 + ct * 16;
            const half8v b0 = *(const half8v*)(Kh + (size_t)(cbase + lo) * HD + qq * 8);
            const half8v b1 = *(const half8v*)(Kh + (size_t)(cbase + lo) * HD + 32 + qq * 8);
            float4v c4 = {0.f, 0.f, 0.f, 0.f};
            c4 = MFMA16(aq0, b0, c4);
            c4 = MFMA16(aq1, b1, c4);
            const int dd0 = cbase - rbase;
            const bool near = (dd0 > -24) && (dd0 < 24);
            #pragma unroll
            for (int r = 0; r < 4; ++r) {
                float s = c4[r] * 0.125f;
                if (near) {
                    const float d = (float)(rbase + qq * 4 + r - cbase - lo);
                    s += __expf(-0.5f * d * d);
                }
                s = fminf(s, 60.f);
                const float e = __expf(s);
                const float p = e * li[r];
                msum[ct][r] += p;
                Ps[(size_t)(rg * 16 + qq * 4 + r) * PS_STRIDE + chw * 128 + ct * 16 + lo] = (half_t)p;
            }
        }
        __syncthreads();   // Vt staged + Ps written
        // ---- PV: O_partial[32][64] for this head ----
        float4v accO[2];
        accO[0] = (float4v){0.f, 0.f, 0.f, 0.f};
        accO[1] = (float4v){0.f, 0.f, 0.f, 0.f};
        #pragma unroll
        for (int ks = 0; ks < 8; ++ks) {
            const half8v ap = *(const half8v*)&Ps[(size_t)(rg * 16 + lo) * PS_STRIDE + ks * 32 + qq * 8];
            #pragma unroll
            for (int dgi = 0; dgi < 2; ++dgi) {
                const int d0 = (chw * 2 + dgi) * 16;
                const size_t voff = (size_t)(d0 + lo) * VT_STRIDE + ks * 32 + qq * 8;
                const half4v u0 = *(const half4v*)&Vt[voff];
                const half4v u1 = *(const half4v*)&Vt[voff + 4];
                half8v bv;
                bv[0] = u0[0]; bv[1] = u0[1]; bv[2] = u0[2]; bv[3] = u0[3];
                bv[4] = u1[0]; bv[5] = u1[1]; bv[6] = u1[2]; bv[7] = u1[3];
                accO[dgi] = MFMA16(ap, bv, accO[dgi]);
            }
        }
        #pragma unroll
        for (int dgi = 0; dgi < 2; ++dgi)
            #pragma unroll
            for (int r = 0; r < 4; ++r)
                po[(size_t)(rbase + qq * 4 + r) * FDIM + h * HD + (chw * 2 + dgi) * 16 + lo] =
                    accO[dgi][r];
    }
    // ---- write mean_weights directly (fp32, Σ_h p/8 accumulated in regs) ----
    #pragma unroll
    for (int ct = 0; ct < 8; ++ct)
        #pragma unroll
        for (int r = 0; r < 4; ++r)
            out[MH_ELEMS + (size_t)(rbase + qq * 4 + r) * S_LEN + c0 + chw * 128 + ct * 16 + lo] =
                msum[ct][r] * 0.125f;
}

// ---------------- Kernel 5: reduce 8 chunk-partials -> multi_head_output ----------------
__global__ __launch_bounds__(256) void reduce_kernel(const float* __restrict__ partial,
                                                     float* __restrict__ out) {
    const size_t i4 = ((size_t)blockIdx.x * 256 + threadIdx.x) * 4;
    float4 s = *(const float4*)(partial + i4);
    #pragma unroll
    for (int c = 1; c < 8; ++c) {
        const float4 t = *(const float4*)(partial + (size_t)c * MH_ELEMS + i4);
        s.x += t.x; s.y += t.y; s.z += t.z; s.w += t.w;
    }
    *(float4*)(out + i4) = s;
}

extern "C" void kernel_launch(void* const* d_in, const int* in_sizes, int n_in,
                              void* d_out, int out_size, void* d_ws, size_t ws_size,
                              hipStream_t stream) {
    const float* x  = (const float*)d_in[0];
    const float* Wq = (const float*)d_in[1];
    const float* Wk = (const float*)d_in[2];
    const float* Wv = (const float*)d_in[3];
    const float* g  = (const float*)d_in[4];
    const float* b  = (const float*)d_in[5];
    float* out = (float*)d_out;
    char*  ws  = (char*)d_ws;

    half_t* xh   = (half_t*)(ws);                  // 2 MB
    half_t* Qh   = (half_t*)(ws + (2ull << 20));   // 2 MB
    half_t* Kh   = (half_t*)(ws + (4ull << 20));   // 2 MB
    half_t* Vh   = (half_t*)(ws + (6ull << 20));   // 2 MB
    float*  linv = (float*)(ws + (8ull << 20));    // 64 KB
    float*  part = (float*)(ws + (9ull << 20));    // 32 MB (8 chunk-partials of 4 MB)

    ln_pe_kernel<<<S_LEN, 256, 0, stream>>>(x, g, b, xh);
    qkv_kernel<<<dim3(16, 8, 3), 256, 0, stream>>>(xh, Wq, Wk, Wv, Qh, Kh, Vh);
    lsum_kernel<<<dim3(128, 8), 256, 0, stream>>>(Qh, Kh, linv);
    attn_kernel<<<dim3(64, 8), 256, 0, stream>>>(Qh, Kh, Vh, linv, part, out);
    reduce_kernel<<<MH_ELEMS / 4 / 256, 256, 0, stream>>>(part, out);
}